// Round 5
// baseline (1349.055 us; speedup 1.0000x reference)
//
#include <hip/hip_runtime.h>

typedef __attribute__((ext_vector_type(4))) float f32x4;
typedef __attribute__((ext_vector_type(8))) short short8;
typedef __attribute__((ext_vector_type(4))) unsigned short ushort4v;

__device__ __forceinline__ unsigned short rne_bf16(float f) {
  unsigned int u = __builtin_bit_cast(unsigned int, f);
  u += 0x7FFFu + ((u >> 16) & 1u);
  return (unsigned short)(u >> 16);
}

__device__ __forceinline__ void async16(void* lds, const void* g) {
  __builtin_amdgcn_global_load_lds(
      (const __attribute__((address_space(1))) void*)g,
      (__attribute__((address_space(3))) void*)lds, 16, 0, 0);
}

__device__ __forceinline__ f32x4 mfma16(short8 a, short8 b, f32x4 c) {
  return __builtin_amdgcn_mfma_f32_16x16x32_bf16(a, b, c, 0, 0, 0);
}

// ---------------- f32 -> bf16 cast (vectorized, grid-stride) ----------------
__global__ __launch_bounds__(256) void cast_k(const float* __restrict__ in,
                                              unsigned short* __restrict__ out,
                                              int n4) {
  int stride = gridDim.x * 256;
  for (int i = blockIdx.x * 256 + threadIdx.x; i < n4; i += stride) {
    float4 v = ((const float4*)in)[i];
    ushort4v o = {rne_bf16(v.x), rne_bf16(v.y), rne_bf16(v.z), rne_bf16(v.w)};
    ((ushort4v*)out)[i] = o;
  }
}

// ============ 256x256-tile GEMM: C = A @ B^T (bf16 in, K%64==0, K>=128) ======
// 8 waves (2M x 4N). 128 KiB LDS = 4 rotating 32KB regions: region Q holds
// (tile Q>>1, kh Q&1) at offset ((Q>>1)&1)*32768 + (Q&1)*8192 (A; B at +16384).
// Rotation ledger (same as R4, passed): phase P stages region P+3; per-phase
// gate vmcnt(4) leaves exactly region P+3's 4 loads in flight, so region P+1
// is retired+published >=1 full phase+barrier before any wave reads it, and
// stages target regions disjoint from all live readers.
// NEW (m201/m196 fine interleave): each phase = two 16-MFMA sub-phases:
//  sub-a: read af[0:4]+bf[0:4] (8 b128) | stage A-pair | barrier | lgkm0 |
//         setprio 16 MFMA (acc rows 0-3) | barrier
//  sub-b: read af[4:8] (4 b128) | stage B-pair | barrier | lgkm0 |
//         setprio 16 MFMA (rows 4-7) | vmcnt(4 or 0) | barrier
// MODE 0: QKV proj -> bf16 head-transposed dst[(b*16+h)][i][tok], *scale
// MODE 3: out proj -> f32 outF[m*4096+n] + bias[n]
template <int MODE>
__global__ __launch_bounds__(512, 2) void gemm256(const unsigned short* __restrict__ A,
                                                  const unsigned short* __restrict__ B,
                                                  float* __restrict__ outF,
                                                  unsigned short* __restrict__ outB,
                                                  const float* __restrict__ bias,
                                                  int K, int lda, int ldb,
                                                  float scale, int gx) {
  __shared__ unsigned short lds[65536];  // 128 KiB
  const int tid = threadIdx.x;
  const int lane = tid & 63;
  const int wid = tid >> 6;
  const int wm = wid >> 2;  // 0..1 -> 128 rows each
  const int wn = wid & 3;   // 0..3 -> 64 cols each
  int lin = blockIdx.x;
  lin = (lin & 7) * (gridDim.x >> 3) + (lin >> 3);  // XCD swizzle (grid%8==0)
  const int bx = lin % gx;
  const int by = lin / gx;
  const int m0 = by * 256, n0 = bx * 256;
  const int NT = K >> 6;

  // staging: thread t covers LDS slot p = tid (+512): row=p>>2, chunk=p&3
  const int gsw8 = (((tid & 3) ^ ((tid >> 3) & 3))) * 8;  // pre-swizzled col
  const unsigned short* gA = A + (size_t)(m0 + (tid >> 2)) * lda + gsw8;
  const unsigned short* gB = B + (size_t)(n0 + (tid >> 2)) * ldb + gsw8;
  const size_t astep = (size_t)128 * lda;
  const size_t bstep = (size_t)128 * ldb;
  unsigned short* ld0 = &lds[tid * 8];

#define STG_A(Q) do { \
    const int kt_ = ((Q) >> 1) * 64 + ((Q) & 1) * 32; \
    const int off_ = (((Q) >> 1) & 1) * 32768 + ((Q) & 1) * 8192; \
    const unsigned short* sA_ = gA + kt_; \
    unsigned short* dA_ = ld0 + off_; \
    async16(dA_, sA_); async16(dA_ + 4096, sA_ + astep); } while (0)
#define STG_B(Q) do { \
    const int kt_ = ((Q) >> 1) * 64 + ((Q) & 1) * 32; \
    const int off_ = 16384 + (((Q) >> 1) & 1) * 32768 + ((Q) & 1) * 8192; \
    const unsigned short* sB_ = gB + kt_; \
    unsigned short* dB_ = ld0 + off_; \
    async16(dB_, sB_); async16(dB_ + 4096, sB_ + bstep); } while (0)

  // ds_read addresses (swizzled chunk; conflict-free)
  const int rl = lane & 15;
  const int ch = (lane >> 4) ^ ((rl >> 1) & 3);
  const int aidx = wm * 4096 + rl * 32 + ch * 8;           // + region base + r*512
  const int bidx = 16384 + wn * 2048 + rl * 32 + ch * 8;   // + region base + s*512

  short8 af[8], bf[4];
#define READ_A4(base, o) do { \
    _Pragma("unroll") \
    for (int r_ = 0; r_ < 4; ++r_) \
      af[(o) + r_] = *(const short8*)&lds[(base) + aidx + ((o) + r_) * 512]; \
  } while (0)
#define READ_B4(base) do { \
    _Pragma("unroll") \
    for (int s_ = 0; s_ < 4; ++s_) bf[s_] = *(const short8*)&lds[(base) + bidx + s_ * 512]; \
  } while (0)

  f32x4 acc[8][4];
#pragma unroll
  for (int r = 0; r < 8; ++r)
#pragma unroll
    for (int s = 0; s < 4; ++s) acc[r][s] = (f32x4){0.f, 0.f, 0.f, 0.f};

#define MFMA16(o) do { \
    _Pragma("unroll") \
    for (int r_ = 0; r_ < 4; ++r_) \
      _Pragma("unroll") \
      for (int s_ = 0; s_ < 4; ++s_) \
        acc[(o) + r_][s_] = mfma16(af[(o) + r_], bf[s_], acc[(o) + r_][s_]); \
  } while (0)

// One kh-phase: two 16-MFMA sub-phases with fine read/stage interleave.
#define PHASE(P_, rb_, doStage_) do { \
    READ_A4((rb_), 0); \
    READ_B4((rb_)); \
    if (doStage_) STG_A((P_) + 3); \
    __builtin_amdgcn_sched_barrier(0); \
    __builtin_amdgcn_s_barrier(); \
    asm volatile("s_waitcnt lgkmcnt(0)" ::: "memory"); \
    __builtin_amdgcn_sched_barrier(0); \
    __builtin_amdgcn_s_setprio(1); \
    MFMA16(0); \
    __builtin_amdgcn_s_setprio(0); \
    __builtin_amdgcn_s_barrier(); \
    READ_A4((rb_), 4); \
    if (doStage_) STG_B((P_) + 3); \
    __builtin_amdgcn_sched_barrier(0); \
    __builtin_amdgcn_s_barrier(); \
    asm volatile("s_waitcnt lgkmcnt(0)" ::: "memory"); \
    __builtin_amdgcn_sched_barrier(0); \
    __builtin_amdgcn_s_setprio(1); \
    MFMA16(4); \
    __builtin_amdgcn_s_setprio(0); \
    if (doStage_) asm volatile("s_waitcnt vmcnt(4)" ::: "memory"); \
    else          asm volatile("s_waitcnt vmcnt(0)" ::: "memory"); \
    __builtin_amdgcn_s_barrier(); \
  } while (0)

  // ---- prologue: stage regions 0,1,2; retire 0,1 (region 2 in flight)
  STG_A(0); STG_B(0); STG_A(1); STG_B(1); STG_A(2); STG_B(2);
  asm volatile("s_waitcnt vmcnt(4)" ::: "memory");
  __builtin_amdgcn_s_barrier();

  const int PMAX = 2 * NT - 1;
  for (int t = 0; t < NT; ++t) {
    const int bb = (t & 1) * 32768;
    PHASE(2 * t,     bb,        (2 * t + 3) <= PMAX);
    PHASE(2 * t + 1, bb + 8192, (2 * t + 4) <= PMAX);
  }
#undef STG_A
#undef STG_B
#undef READ_A4
#undef READ_B4
#undef MFMA16
#undef PHASE

  // ---- epilogue: C frag col = lane&15, row = (lane>>4)*4 + j
  const int fcol = lane & 15;
  const int frow = (lane >> 4) * 4;
#pragma unroll
  for (int r = 0; r < 8; ++r) {
#pragma unroll
    for (int s = 0; s < 4; ++s) {
      f32x4 v = acc[r][s];
      const int m = m0 + wm * 128 + r * 16 + frow;
      const int n = n0 + wn * 64 + s * 16 + fcol;
      if (MODE == 0) {
        ushort4v p;
#pragma unroll
        for (int j = 0; j < 4; ++j) p[j] = rne_bf16(v[j] * scale);
        size_t d = ((size_t)((m >> 8) * 16 + (n >> 8))) * 65536 +
                   (size_t)(n & 255) * 256 + (m & 255);
        *(ushort4v*)&outB[d] = p;
      } else {
        float bv = bias[n];
#pragma unroll
        for (int j = 0; j < 4; ++j) outF[(size_t)(m + j) * 4096 + n] = v[j] + bv;
      }
    }
  }
}

// ---------------- 128x128 GEMM for the small batched mats --------------------
// MODE 1: S = q^T k (batched by z) -> f32 at outF + z*65536, ldc=256
// MODE 2: PV (batched by z)        -> bf16 out_x[((z>>4)*256+m)*4096+(z&15)*256+n]
template <int MODE>
__global__ __launch_bounds__(256) void gemm_bt(const unsigned short* __restrict__ Ab,
                                               const unsigned short* __restrict__ Bb,
                                               float* __restrict__ outF,
                                               unsigned short* __restrict__ outB,
                                               int K, int lda, int ldb) {
  __shared__ short Ash[128 * 32];
  __shared__ short Bsh[128 * 32];

  const int tid = threadIdx.x;
  const int lane = tid & 63;
  const int wid = tid >> 6;
  const int z = blockIdx.z;
  const int m0 = blockIdx.y * 128;
  const int n0 = blockIdx.x * 128;

  const unsigned short* A = Ab + (size_t)z * 65536;
  const unsigned short* B = Bb + (size_t)z * 65536;

  const int wm = (wid >> 1) * 64;
  const int wn = (wid & 1) * 64;
  const int fcol = lane & 15;
  const int kslot = (lane >> 4) * 8;

  f32x4 acc[4][4];
#pragma unroll
  for (int r = 0; r < 4; ++r)
#pragma unroll
    for (int s = 0; s < 4; ++s) acc[r][s] = (f32x4){0.f, 0.f, 0.f, 0.f};

  const int arow = tid >> 2;
  const int acol = (tid & 3) * 8;
  const unsigned short* gA = A + (size_t)(m0 + arow) * lda + acol;
  const unsigned short* gB = B + (size_t)(n0 + arow) * ldb + acol;
  short* lA = &Ash[tid * 8];
  short* lB = &Bsh[tid * 8];

  for (int kt = 0; kt < K; kt += 32) {
    __syncthreads();
    async16(lA, gA + kt);
    async16(lA + 2048, gA + (size_t)64 * lda + kt);
    async16(lB, gB + kt);
    async16(lB + 2048, gB + (size_t)64 * ldb + kt);
    __syncthreads();

    short8 a[4], b[4];
#pragma unroll
    for (int r = 0; r < 4; ++r)
      a[r] = *(const short8*)&Ash[(wm + r * 16 + fcol) * 32 + kslot];
#pragma unroll
    for (int s = 0; s < 4; ++s)
      b[s] = *(const short8*)&Bsh[(wn + s * 16 + fcol) * 32 + kslot];
#pragma unroll
    for (int r = 0; r < 4; ++r)
#pragma unroll
      for (int s = 0; s < 4; ++s)
        acc[r][s] = __builtin_amdgcn_mfma_f32_16x16x32_bf16(a[r], b[s], acc[r][s], 0, 0, 0);
  }

  const int frow = (lane >> 4) * 4;
#pragma unroll
  for (int r = 0; r < 4; ++r) {
#pragma unroll
    for (int s = 0; s < 4; ++s) {
      f32x4 v = acc[r][s];
      const int m = m0 + wm + r * 16 + frow;
      const int n = n0 + wn + s * 16 + fcol;
      if (MODE == 1) {
        float* C = outF + (size_t)z * 65536;
#pragma unroll
        for (int j = 0; j < 4; ++j) C[(size_t)(m + j) * 256 + n] = v[j];
      } else {
        size_t base = ((size_t)((z >> 4) * 256 + m)) * 4096 + (z & 15) * 256 + n;
#pragma unroll
        for (int j = 0; j < 4; ++j) outB[base + (size_t)j * 4096] = rne_bf16(v[j]);
      }
    }
  }
}

// ---------------- row softmax over 256, in-place f32 + bf16 copy -------------
__global__ __launch_bounds__(256) void softmax_k(float* __restrict__ S,
                                                 unsigned short* __restrict__ P) {
  const int lane = threadIdx.x & 63;
  const size_t row = (size_t)blockIdx.x * 4 + (threadIdx.x >> 6);
  float4 x = *(const float4*)&S[row * 256 + lane * 4];
  float mx = fmaxf(fmaxf(x.x, x.y), fmaxf(x.z, x.w));
#pragma unroll
  for (int off = 32; off; off >>= 1) mx = fmaxf(mx, __shfl_xor(mx, off, 64));
  float e0 = __expf(x.x - mx), e1 = __expf(x.y - mx);
  float e2 = __expf(x.z - mx), e3 = __expf(x.w - mx);
  float s = e0 + e1 + e2 + e3;
#pragma unroll
  for (int off = 32; off; off >>= 1) s += __shfl_xor(s, off, 64);
  const float inv = 1.0f / s;
  e0 *= inv; e1 *= inv; e2 *= inv; e3 *= inv;
  *(float4*)&S[row * 256 + lane * 4] = make_float4(e0, e1, e2, e3);
  ushort4v ob = {rne_bf16(e0), rne_bf16(e1), rne_bf16(e2), rne_bf16(e3)};
  *(ushort4v*)&P[row * 256 + lane * 4] = ob;
}

// -----------------------------------------------------------------------------
extern "C" void kernel_launch(void* const* d_in, const int* in_sizes, int n_in,
                              void* d_out, int out_size, void* d_ws, size_t ws_size,
                              hipStream_t stream) {
  const float* x1 = (const float*)d_in[0];
  const float* x2 = (const float*)d_in[1];
  const float* Wq = (const float*)d_in[2];
  const float* Wk = (const float*)d_in[3];
  const float* Wv = (const float*)d_in[4];
  const float* Wp = (const float*)d_in[5];
  const float* bp = (const float*)d_in[6];

  float* outX = (float*)d_out;                   // x: [8192,4096] f32
  float* outA = outX + (size_t)33554432;         // attn: [512,256,256] f32

  unsigned short* Qt  = (unsigned short*)d_ws;   // [512][256][256] head-transposed
  unsigned short* Kt  = Qt + 33554432;
  unsigned short* Vt  = Kt + 33554432;
  unsigned short* x1b = Vt + 33554432;           // x1 bf16; later attn bf16
  unsigned short* x2b = x1b + 33554432;          // x2 bf16; later out_x bf16
  unsigned short* Wb  = x2b + 33554432;          // current weight bf16 [4096,4096]

  const float SCALE = 0.0625f;  // 256^-0.5

  cast_k<<<2048, 256, 0, stream>>>(x1, x1b, 8388608);
  cast_k<<<2048, 256, 0, stream>>>(x2, x2b, 8388608);

  // Q = (x1 @ Wq^T) * SCALE -> Qt[b,h,i,tok]
  cast_k<<<2048, 256, 0, stream>>>(Wq, Wb, 4194304);
  gemm256<0><<<512, 512, 0, stream>>>(x1b, Wb, nullptr, Qt, nullptr,
                                      4096, 4096, 4096, SCALE, 16);
  // K = x2 @ Wk^T -> Kt
  cast_k<<<2048, 256, 0, stream>>>(Wk, Wb, 4194304);
  gemm256<0><<<512, 512, 0, stream>>>(x2b, Wb, nullptr, Kt, nullptr,
                                      4096, 4096, 4096, 1.0f, 16);
  // V = x2 @ Wv^T -> Vt
  cast_k<<<2048, 256, 0, stream>>>(Wv, Wb, 4194304);
  gemm256<0><<<512, 512, 0, stream>>>(x2b, Wb, nullptr, Vt, nullptr,
                                      4096, 4096, 4096, 1.0f, 16);

  // S = q^T k per head -> f32 logits into d_out attn region
  gemm_bt<1><<<dim3(2, 2, 512), 256, 0, stream>>>(Qt, Kt, outA, nullptr, 256, 256, 256);
  // softmax rows in-place; bf16 attn copy into x1b
  softmax_k<<<32768, 256, 0, stream>>>(outA, x1b);
  // out = attn @ v per head -> bf16 x-layout into x2b
  gemm_bt<2><<<dim3(2, 2, 512), 256, 0, stream>>>(x1b, Vt, nullptr, x2b, 256, 256, 256);

  // x = out @ Wp^T + bp -> d_out
  cast_k<<<2048, 256, 0, stream>>>(Wp, Wb, 4194304);
  gemm256<3><<<512, 512, 0, stream>>>(x2b, Wb, outX, nullptr, bp,
                                      4096, 4096, 4096, 1.0f, 16);
}